// Round 2
// baseline (108.133 us; speedup 1.0000x reference)
//
#include <hip/hip_runtime.h>

#define NP 100000
#define MP 32
#define OC 64
#define BNEPS 0.001f
#define FIXS_S 65536.0f           // 2^16 fixed-point for Sigma h  (|S|~1e9 -> 6e13, exact-enough)
#define FIXS_Q 256.0f             // 2^8  fixed-point for Sigma h^2 (Q~1e12-1e13 -> <1e16, no overflow)
#define MTOT 3200000.0            // N * P positions for BN mean/var

// ---------------------------------------------------------------------------
// Pass 1: wave-per-pillar, lane = output channel.
// Computes per-pillar {Sigma f, Sigma d'^2, max d'} with gamma-sign folded into
// the weights, emits hsel[n][c] = (gamma>=0 ? max_p h : min_p h) incl. the
// masked-position zero, and accumulates global Sigma h / Sigma h^2 as int64
// fixed-point atomics (deterministic).
// ---------------------------------------------------------------------------
__global__ __launch_bounds__(256) void sap_pass1(
    const float* __restrict__ feat, const float* __restrict__ W,
    const float* __restrict__ gamma, const int* __restrict__ nump,
    const int* __restrict__ coors, float* __restrict__ hsel,
    unsigned long long* __restrict__ accum)
{
    const int lane = threadIdx.x & 63;
    const int wid  = threadIdx.x >> 6;
    const int c = lane;

    // W is (10, 64) row-major. Fold cluster/center weights: W2 = W[k]+W[4+k]+W[7+k].
    float w2[4], wcl[3], wce[3];
    w2[3] = W[3 * OC + c];
    #pragma unroll
    for (int k = 0; k < 3; ++k) {
        wcl[k] = W[(4 + k) * OC + c];
        wce[k] = W[(7 + k) * OC + c];
        w2[k]  = W[k * OC + c] + wcl[k] + wce[k];
    }
    // Fold sign(gamma) so we only ever track a running MAX of d' = sgn*d.
    const float sgn = (gamma[c] >= 0.0f) ? 1.0f : -1.0f;
    #pragma unroll
    for (int k = 0; k < 3; ++k) { wcl[k] *= sgn; wce[k] *= sgn; w2[k] *= sgn; }
    w2[3] *= sgn;

    float accS = 0.0f, accQ = 0.0f;
    const int stride = gridDim.x * 4;
    for (int nn = blockIdx.x * 4 + wid; nn < NP; nn += stride) {
        const int n = __builtin_amdgcn_readfirstlane(nn);   // wave-uniform pillar
        const int cnt = nump[n];                            // uniform scalar load
        const float4* __restrict__ f4 =
            reinterpret_cast<const float4*>(feat) + (size_t)n * MP;

        float sf0 = 0.f, sf1 = 0.f, sf2 = 0.f, sf3 = 0.f;
        float q = 0.0f;
        float m = -3.0e38f;
        for (int p = 0; p < cnt; ++p) {                     // uniform trip count
            const float4 f = f4[p];                         // uniform addr -> scalar load
            sf0 += f.x; sf1 += f.y; sf2 += f.z; sf3 += f.w;
            const float d = f.x * w2[0] + f.y * w2[1] + f.z * w2[2] + f.w * w2[3];
            q = fmaf(d, d, q);
            m = fmaxf(m, d);
        }

        const float fcnt = (float)cnt;
        const float rc = 1.0f / fcnt;
        const float cz = ((float)coors[4 * n + 1] + 0.5f) * 0.2f;
        const float cy = ((float)coors[4 * n + 2] + 0.5f) * 0.2f;
        const float cx = ((float)coors[4 * n + 3] + 0.5f) * 4.0f;
        // bias' = sgn * (-mean.Wcl - center.Wce)   (sgn already folded into wcl/wce)
        const float bias = -(sf0 * rc * wcl[0] + sf1 * rc * wcl[1] + sf2 * rc * wcl[2])
                           - (cz * wce[0] + cy * wce[1] + cx * wce[2]);
        const float ssum = sf0 * w2[0] + sf1 * w2[1] + sf2 * w2[2] + sf3 * w2[3]; // Sigma d'

        float hm = m + bias;                  // max over active of h' = sgn*h
        if (cnt < MP) hm = fmaxf(hm, 0.0f);   // masked positions contribute h=0
        hsel[(size_t)n * OC + c] = sgn * hm;

        accS += sgn * (ssum + fcnt * bias);                      // Sigma h (true sign)
        accQ += q + 2.0f * bias * ssum + fcnt * bias * bias;     // Sigma h^2 (sign-free)
    }

    __shared__ float sred[4][128];
    sred[wid][c]      = accS;
    sred[wid][64 + c] = accQ;
    __syncthreads();
    if (wid == 0) {
        const float s  = sred[0][lane] + sred[1][lane] + sred[2][lane] + sred[3][lane];
        const float sq = sred[0][64+lane] + sred[1][64+lane] + sred[2][64+lane] + sred[3][64+lane];
        atomicAdd(&accum[lane],      (unsigned long long)(long long)llrintf(s  * FIXS_S));
        atomicAdd(&accum[64 + lane], (unsigned long long)(long long)llrintf(sq * FIXS_Q));
    }
}

// ---------------------------------------------------------------------------
// Finalize BN stats -> per-channel scale/shift (128 floats).
// ---------------------------------------------------------------------------
__global__ void sap_finalize(const unsigned long long* __restrict__ accum,
                             const float* __restrict__ gamma,
                             const float* __restrict__ beta,
                             float* __restrict__ scsh)
{
    const int c = threadIdx.x;
    const double S = (double)(long long)accum[c]      * (1.0 / 65536.0);
    const double Q = (double)(long long)accum[64 + c] * (1.0 / 256.0);
    const double mu_d = S / MTOT;
    const double var_d = Q / MTOT - mu_d * mu_d;
    const float mu  = (float)mu_d;
    const float sc  = gamma[c] * rsqrtf((float)var_d + BNEPS);
    const float sh  = beta[c] - mu * sc;
    scsh[c]      = sc;
    scsh[64 + c] = sh;
}

// ---------------------------------------------------------------------------
// Pass 2: in-place over d_out: out = relu(scale * hsel + shift).
// ---------------------------------------------------------------------------
__global__ __launch_bounds__(256) void sap_pass2(const float* __restrict__ scsh,
                                                 float* __restrict__ out)
{
    const int idx = blockIdx.x * 256 + threadIdx.x;
    if (idx >= (NP * OC) / 4) return;
    float4 h = reinterpret_cast<float4*>(out)[idx];
    const int ci = idx & 15;                               // channel quad (64ch/4)
    const float4 sc = reinterpret_cast<const float4*>(scsh)[ci];
    const float4 sh = reinterpret_cast<const float4*>(scsh + 64)[ci];
    float4 o;
    o.x = fmaxf(fmaf(h.x, sc.x, sh.x), 0.0f);
    o.y = fmaxf(fmaf(h.y, sc.y, sh.y), 0.0f);
    o.z = fmaxf(fmaf(h.z, sc.z, sh.z), 0.0f);
    o.w = fmaxf(fmaf(h.w, sc.w, sh.w), 0.0f);
    reinterpret_cast<float4*>(out)[idx] = o;
}

extern "C" void kernel_launch(void* const* d_in, const int* in_sizes, int n_in,
                              void* d_out, int out_size, void* d_ws, size_t ws_size,
                              hipStream_t stream) {
    const float* feat  = (const float*)d_in[0];
    const float* W     = (const float*)d_in[1];
    const float* gamma = (const float*)d_in[2];
    const float* beta  = (const float*)d_in[3];
    const int*   nump  = (const int*)d_in[4];
    const int*   coors = (const int*)d_in[5];
    float* out = (float*)d_out;

    unsigned long long* accum = (unsigned long long*)d_ws;   // 128 * 8B
    float* scsh = (float*)((char*)d_ws + 1024);              // 128 * 4B

    hipMemsetAsync(accum, 0, 1024, stream);
    // Pass 1 writes its per-pillar max/min selection straight into d_out.
    sap_pass1<<<1024, 256, 0, stream>>>(feat, W, gamma, nump, coors, out, accum);
    sap_finalize<<<1, 64, 0, stream>>>(accum, gamma, beta, scsh);
    sap_pass2<<<(NP * OC / 4 + 255) / 256, 256, 0, stream>>>(scsh, out);
}

// Round 3
// 101.004 us; speedup vs baseline: 1.0706x; 1.0706x over previous
//
#include <hip/hip_runtime.h>

#define NP 100000
#define MP 32
#define OC 64
#define BNEPS 0.001f
#define FIXS_S 65536.0f           // 2^16 fixed-point for Sigma h
#define FIXS_Q 256.0f             // 2^8  fixed-point for Sigma h^2 (no int64 overflow)
#define MTOT 3200000.0            // N * P positions for BN mean/var

// ---------------------------------------------------------------------------
// Pass 1: wave-per-pillar-slice, lane = output channel.
// 4-way unrolled point loop with independent accumulator sets for ILP.
// ---------------------------------------------------------------------------
__global__ __launch_bounds__(256) void sap_pass1(
    const float* __restrict__ feat, const float* __restrict__ W,
    const float* __restrict__ gamma, const int* __restrict__ nump,
    const int* __restrict__ coors, float* __restrict__ hsel,
    unsigned long long* __restrict__ accum)
{
    const int lane = threadIdx.x & 63;
    const int wid  = threadIdx.x >> 6;
    const int c = lane;

    // W is (10, 64) row-major. Fold cluster/center weights: W2 = W[k]+W[4+k]+W[7+k].
    float w2[4], wcl[3], wce[3];
    w2[3] = W[3 * OC + c];
    #pragma unroll
    for (int k = 0; k < 3; ++k) {
        wcl[k] = W[(4 + k) * OC + c];
        wce[k] = W[(7 + k) * OC + c];
        w2[k]  = W[k * OC + c] + wcl[k] + wce[k];
    }
    // Fold sign(gamma) so we only ever track a running MAX of d' = sgn*d.
    const float sgn = (gamma[c] >= 0.0f) ? 1.0f : -1.0f;
    #pragma unroll
    for (int k = 0; k < 3; ++k) { wcl[k] *= sgn; wce[k] *= sgn; w2[k] *= sgn; }
    w2[3] *= sgn;

    float accS = 0.0f, accQ = 0.0f;
    const int stride = gridDim.x * 4;
    for (int nn = blockIdx.x * 4 + wid; nn < NP; nn += stride) {
        const int n = __builtin_amdgcn_readfirstlane(nn);   // wave-uniform pillar
        const int cnt = nump[n];                            // uniform scalar load
        const float4* __restrict__ f4 =
            reinterpret_cast<const float4*>(feat) + (size_t)n * MP;

        // 4 independent accumulator sets (ILP: 4 loads in flight, 4x shorter chains)
        float sx0=0.f,sy0=0.f,sz0=0.f,sw0=0.f, q0=0.f, m0=-3.0e38f;
        float sx1=0.f,sy1=0.f,sz1=0.f,sw1=0.f, q1=0.f, m1=-3.0e38f;
        float sx2=0.f,sy2=0.f,sz2=0.f,sw2=0.f, q2=0.f, m2=-3.0e38f;
        float sx3=0.f,sy3=0.f,sz3=0.f,sw3=0.f, q3=0.f, m3=-3.0e38f;

#define PT(J, S) { const float4 f = f4[p + J];                                  \
        sx##S += f.x; sy##S += f.y; sz##S += f.z; sw##S += f.w;                 \
        const float d = fmaf(f.x, w2[0], fmaf(f.y, w2[1],                       \
                        fmaf(f.z, w2[2], f.w * w2[3])));                        \
        q##S = fmaf(d, d, q##S); m##S = fmaxf(m##S, d); }

        int p = 0;
        for (; p + 4 <= cnt; p += 4) { PT(0,0) PT(1,1) PT(2,2) PT(3,3) }
        for (; p < cnt; ++p)          { PT(0,0) }
#undef PT

        const float sf0 = (sx0 + sx1) + (sx2 + sx3);
        const float sf1 = (sy0 + sy1) + (sy2 + sy3);
        const float sf2 = (sz0 + sz1) + (sz2 + sz3);
        const float sf3 = (sw0 + sw1) + (sw2 + sw3);
        const float q   = (q0 + q1) + (q2 + q3);
        const float m   = fmaxf(fmaxf(m0, m1), fmaxf(m2, m3));

        const float fcnt = (float)cnt;
        const float rc = 1.0f / fcnt;
        const float cz = ((float)coors[4 * n + 1] + 0.5f) * 0.2f;
        const float cy = ((float)coors[4 * n + 2] + 0.5f) * 0.2f;
        const float cx = ((float)coors[4 * n + 3] + 0.5f) * 4.0f;
        // bias' = sgn * (-mean.Wcl - center.Wce)   (sgn already folded into wcl/wce)
        const float bias = -(sf0 * rc * wcl[0] + sf1 * rc * wcl[1] + sf2 * rc * wcl[2])
                           - (cz * wce[0] + cy * wce[1] + cx * wce[2]);
        const float ssum = sf0 * w2[0] + sf1 * w2[1] + sf2 * w2[2] + sf3 * w2[3]; // Sigma d'

        float hm = m + bias;                  // max over active of h' = sgn*h
        if (cnt < MP) hm = fmaxf(hm, 0.0f);   // masked positions contribute h=0
        hsel[(size_t)n * OC + c] = sgn * hm;

        accS += sgn * (ssum + fcnt * bias);                      // Sigma h (true sign)
        accQ += q + 2.0f * bias * ssum + fcnt * bias * bias;     // Sigma h^2 (sign-free)
    }

    __shared__ float sred[4][128];
    sred[wid][c]      = accS;
    sred[wid][64 + c] = accQ;
    __syncthreads();
    if (wid == 0) {
        const float s  = sred[0][lane] + sred[1][lane] + sred[2][lane] + sred[3][lane];
        const float sq = sred[0][64+lane] + sred[1][64+lane] + sred[2][64+lane] + sred[3][64+lane];
        atomicAdd(&accum[lane],      (unsigned long long)(long long)llrintf(s  * FIXS_S));
        atomicAdd(&accum[64 + lane], (unsigned long long)(long long)llrintf(sq * FIXS_Q));
    }
}

// ---------------------------------------------------------------------------
// Finalize BN stats -> per-channel scale/shift (128 floats).
// ---------------------------------------------------------------------------
__global__ void sap_finalize(const unsigned long long* __restrict__ accum,
                             const float* __restrict__ gamma,
                             const float* __restrict__ beta,
                             float* __restrict__ scsh)
{
    const int c = threadIdx.x;
    const double S = (double)(long long)accum[c]      * (1.0 / 65536.0);
    const double Q = (double)(long long)accum[64 + c] * (1.0 / 256.0);
    const double mu_d = S / MTOT;
    const double var_d = Q / MTOT - mu_d * mu_d;
    const float mu  = (float)mu_d;
    const float sc  = gamma[c] * rsqrtf((float)var_d + BNEPS);
    const float sh  = beta[c] - mu * sc;
    scsh[c]      = sc;
    scsh[64 + c] = sh;
}

// ---------------------------------------------------------------------------
// Pass 2: in-place over d_out: out = relu(scale * hsel + shift).
// ---------------------------------------------------------------------------
__global__ __launch_bounds__(256) void sap_pass2(const float* __restrict__ scsh,
                                                 float* __restrict__ out)
{
    const int idx = blockIdx.x * 256 + threadIdx.x;
    if (idx >= (NP * OC) / 4) return;
    float4 h = reinterpret_cast<float4*>(out)[idx];
    const int ci = idx & 15;                               // channel quad (64ch/4)
    const float4 sc = reinterpret_cast<const float4*>(scsh)[ci];
    const float4 sh = reinterpret_cast<const float4*>(scsh + 64)[ci];
    float4 o;
    o.x = fmaxf(fmaf(h.x, sc.x, sh.x), 0.0f);
    o.y = fmaxf(fmaf(h.y, sc.y, sh.y), 0.0f);
    o.z = fmaxf(fmaf(h.z, sc.z, sh.z), 0.0f);
    o.w = fmaxf(fmaf(h.w, sc.w, sh.w), 0.0f);
    reinterpret_cast<float4*>(out)[idx] = o;
}

extern "C" void kernel_launch(void* const* d_in, const int* in_sizes, int n_in,
                              void* d_out, int out_size, void* d_ws, size_t ws_size,
                              hipStream_t stream) {
    const float* feat  = (const float*)d_in[0];
    const float* W     = (const float*)d_in[1];
    const float* gamma = (const float*)d_in[2];
    const float* beta  = (const float*)d_in[3];
    const int*   nump  = (const int*)d_in[4];
    const int*   coors = (const int*)d_in[5];
    float* out = (float*)d_out;

    unsigned long long* accum = (unsigned long long*)d_ws;   // 128 * 8B
    float* scsh = (float*)((char*)d_ws + 1024);              // 128 * 4B

    hipMemsetAsync(accum, 0, 1024, stream);
    // Pass 1 writes its per-pillar max/min selection straight into d_out.
    sap_pass1<<<2048, 256, 0, stream>>>(feat, W, gamma, nump, coors, out, accum);
    sap_finalize<<<1, 64, 0, stream>>>(accum, gamma, beta, scsh);
    sap_pass2<<<(NP * OC / 4 + 255) / 256, 256, 0, stream>>>(scsh, out);
}

// Round 4
// 88.465 us; speedup vs baseline: 1.2223x; 1.1417x over previous
//
#include <hip/hip_runtime.h>
#include <stdint.h>

#define NP 100000
#define MP 32
#define OC 64
#define PPB 16                    // pillars per LDS chunk (16*512B = 8KB)
#define NCHUNK (NP / PPB)         // 6250 (exact)
#define GRID1 2048
#define BNEPS 0.001f
#define FIXS_S 65536.0f           // 2^16 fixed-point for Sigma h
#define FIXS_Q 256.0f             // 2^8  fixed-point for Sigma h^2 (no int64 overflow)
#define MTOT 3200000.0

typedef __attribute__((address_space(3))) uint32_t as3_u32;
typedef const __attribute__((address_space(1))) uint32_t as1_u32;

// ---------------------------------------------------------------------------
// Pass 1: block stages 16 pillars into LDS (coalesced global_load_lds x16B),
// each wave computes 4 pillars from LDS broadcasts; lane = output channel.
// Emits hsel[n][c] = (gamma>=0 ? max_p h : min_p h) into d_out and global
// Sigma h / Sigma h^2 as deterministic int64 fixed-point atomics.
// ---------------------------------------------------------------------------
__global__ __launch_bounds__(256) void sap_pass1(
    const float* __restrict__ feat, const float* __restrict__ W,
    const float* __restrict__ gamma, const int* __restrict__ nump,
    const int* __restrict__ coors, float* __restrict__ hsel,
    unsigned long long* __restrict__ accum)
{
    __shared__ float lds[PPB * MP * 4];   // 8 KB
    const int tid  = threadIdx.x;
    const int lane = tid & 63;
    const int wid  = tid >> 6;
    const int c = lane;

    // W is (10, 64) row-major. Fold cluster/center weights: W2 = W[k]+W[4+k]+W[7+k].
    float w2[4], wcl[3], wce[3];
    w2[3] = W[3 * OC + c];
    #pragma unroll
    for (int k = 0; k < 3; ++k) {
        wcl[k] = W[(4 + k) * OC + c];
        wce[k] = W[(7 + k) * OC + c];
        w2[k]  = W[k * OC + c] + wcl[k] + wce[k];
    }
    // Fold sign(gamma): track a running MAX of d' = sgn*d only.
    const float sgn = (gamma[c] >= 0.0f) ? 1.0f : -1.0f;
    #pragma unroll
    for (int k = 0; k < 3; ++k) { wcl[k] *= sgn; wce[k] *= sgn; w2[k] *= sgn; }
    w2[3] *= sgn;

    float accS = 0.0f, accQ = 0.0f;

    for (int chunk = blockIdx.x; chunk < NCHUNK; chunk += GRID1) {
        // ---- stage: 256 threads x 2 x 16B = 8KB, coalesced, direct-to-LDS
        {
            const char* g = (const char*)feat + (size_t)chunk * (PPB * MP * 16) + tid * 16;
            as3_u32* l = (as3_u32*)(&lds[0]);
            __builtin_amdgcn_global_load_lds((as1_u32*)(g),        l + tid * 4,        16, 0, 0);
            __builtin_amdgcn_global_load_lds((as1_u32*)(g + 4096), l + 1024 + tid * 4, 16, 0, 0);
        }
        __syncthreads();   // drains vmcnt(0): chunk resident

        // ---- compute: wave wid owns pillars [wid*4, wid*4+4)
        #pragma unroll
        for (int jj = 0; jj < 4; ++jj) {
            const int n = chunk * PPB + wid * 4 + jj;      // wave-uniform
            const int cnt = nump[n];                       // uniform -> s_load
            const float4* __restrict__ f4 =
                reinterpret_cast<const float4*>(&lds[(wid * 4 + jj) * MP * 4]);

            float sx0=0.f,sy0=0.f,sz0=0.f,sw0=0.f, q0=0.f, m0=-3.0e38f;
            float sx1=0.f,sy1=0.f,sz1=0.f,sw1=0.f, q1=0.f, m1=-3.0e38f;
            float sx2=0.f,sy2=0.f,sz2=0.f,sw2=0.f, q2=0.f, m2=-3.0e38f;
            float sx3=0.f,sy3=0.f,sz3=0.f,sw3=0.f, q3=0.f, m3=-3.0e38f;

#define PT(J, S) { const float4 f = f4[p + J];                                  \
            sx##S += f.x; sy##S += f.y; sz##S += f.z; sw##S += f.w;             \
            const float d = fmaf(f.x, w2[0], fmaf(f.y, w2[1],                   \
                            fmaf(f.z, w2[2], f.w * w2[3])));                    \
            q##S = fmaf(d, d, q##S); m##S = fmaxf(m##S, d); }

            int p = 0;
            for (; p + 4 <= cnt; p += 4) { PT(0,0) PT(1,1) PT(2,2) PT(3,3) }
            for (; p < cnt; ++p)          { PT(0,0) }
#undef PT

            const float sf0 = (sx0 + sx1) + (sx2 + sx3);
            const float sf1 = (sy0 + sy1) + (sy2 + sy3);
            const float sf2 = (sz0 + sz1) + (sz2 + sz3);
            const float sf3 = (sw0 + sw1) + (sw2 + sw3);
            const float q   = (q0 + q1) + (q2 + q3);
            const float m   = fmaxf(fmaxf(m0, m1), fmaxf(m2, m3));

            const float fcnt = (float)cnt;
            const float rc = 1.0f / fcnt;
            const float cz = ((float)coors[4 * n + 1] + 0.5f) * 0.2f;
            const float cy = ((float)coors[4 * n + 2] + 0.5f) * 0.2f;
            const float cx = ((float)coors[4 * n + 3] + 0.5f) * 4.0f;
            // bias' = sgn * (-mean.Wcl - center.Wce)  (sgn folded into wcl/wce)
            const float bias = -(sf0 * rc * wcl[0] + sf1 * rc * wcl[1] + sf2 * rc * wcl[2])
                               - (cz * wce[0] + cy * wce[1] + cx * wce[2]);
            const float ssum = sf0 * w2[0] + sf1 * w2[1] + sf2 * w2[2] + sf3 * w2[3];

            float hm = m + bias;                  // max over active of h' = sgn*h
            if (cnt < MP) hm = fmaxf(hm, 0.0f);   // masked positions contribute h=0
            hsel[(size_t)n * OC + c] = sgn * hm;

            accS += sgn * (ssum + fcnt * bias);                   // Sigma h
            accQ += q + 2.0f * bias * ssum + fcnt * bias * bias;  // Sigma h^2
        }
        __syncthreads();   // all waves done reading lds before next stage
    }

    __shared__ float sred[4][128];
    sred[wid][c]      = accS;
    sred[wid][64 + c] = accQ;
    __syncthreads();
    if (wid == 0) {
        const float s  = sred[0][lane] + sred[1][lane] + sred[2][lane] + sred[3][lane];
        const float sq = sred[0][64+lane] + sred[1][64+lane] + sred[2][64+lane] + sred[3][64+lane];
        atomicAdd(&accum[lane],      (unsigned long long)(long long)llrintf(s  * FIXS_S));
        atomicAdd(&accum[64 + lane], (unsigned long long)(long long)llrintf(sq * FIXS_Q));
    }
}

// ---------------------------------------------------------------------------
// Finalize BN stats -> per-channel scale/shift (128 floats).
// ---------------------------------------------------------------------------
__global__ void sap_finalize(const unsigned long long* __restrict__ accum,
                             const float* __restrict__ gamma,
                             const float* __restrict__ beta,
                             float* __restrict__ scsh)
{
    const int c = threadIdx.x;
    const double S = (double)(long long)accum[c]      * (1.0 / 65536.0);
    const double Q = (double)(long long)accum[64 + c] * (1.0 / 256.0);
    const double mu_d = S / MTOT;
    const double var_d = Q / MTOT - mu_d * mu_d;
    const float mu  = (float)mu_d;
    const float sc  = gamma[c] * rsqrtf((float)var_d + BNEPS);
    const float sh  = beta[c] - mu * sc;
    scsh[c]      = sc;
    scsh[64 + c] = sh;
}

// ---------------------------------------------------------------------------
// Pass 2: in-place over d_out: out = relu(scale * hsel + shift).
// ---------------------------------------------------------------------------
__global__ __launch_bounds__(256) void sap_pass2(const float* __restrict__ scsh,
                                                 float* __restrict__ out)
{
    const int idx = blockIdx.x * 256 + threadIdx.x;
    if (idx >= (NP * OC) / 4) return;
    float4 h = reinterpret_cast<float4*>(out)[idx];
    const int ci = idx & 15;                               // channel quad (64ch/4)
    const float4 sc = reinterpret_cast<const float4*>(scsh)[ci];
    const float4 sh = reinterpret_cast<const float4*>(scsh + 64)[ci];
    float4 o;
    o.x = fmaxf(fmaf(h.x, sc.x, sh.x), 0.0f);
    o.y = fmaxf(fmaf(h.y, sc.y, sh.y), 0.0f);
    o.z = fmaxf(fmaf(h.z, sc.z, sh.z), 0.0f);
    o.w = fmaxf(fmaf(h.w, sc.w, sh.w), 0.0f);
    reinterpret_cast<float4*>(out)[idx] = o;
}

extern "C" void kernel_launch(void* const* d_in, const int* in_sizes, int n_in,
                              void* d_out, int out_size, void* d_ws, size_t ws_size,
                              hipStream_t stream) {
    const float* feat  = (const float*)d_in[0];
    const float* W     = (const float*)d_in[1];
    const float* gamma = (const float*)d_in[2];
    const float* beta  = (const float*)d_in[3];
    const int*   nump  = (const int*)d_in[4];
    const int*   coors = (const int*)d_in[5];
    float* out = (float*)d_out;

    unsigned long long* accum = (unsigned long long*)d_ws;   // 128 * 8B
    float* scsh = (float*)((char*)d_ws + 1024);              // 128 * 4B

    hipMemsetAsync(accum, 0, 1024, stream);
    // Pass 1 writes its per-pillar max/min selection straight into d_out.
    sap_pass1<<<GRID1, 256, 0, stream>>>(feat, W, gamma, nump, coors, out, accum);
    sap_finalize<<<1, 64, 0, stream>>>(accum, gamma, beta, scsh);
    sap_pass2<<<(NP * OC / 4 + 255) / 256, 256, 0, stream>>>(scsh, out);
}